// Round 9
// baseline (4246.138 us; speedup 1.0000x reference)
//
#include <hip/hip_runtime.h>
#include <hip/hip_bf16.h>
#include <math.h>

#define VB 50000
#define EE 256
#define UU 512
#define BB 256
#define TT 256
#define G4 2048

typedef __attribute__((ext_vector_type(8))) short short8;
typedef __attribute__((ext_vector_type(4))) float f32x4;

__device__ __forceinline__ float sigf(float x){ return 1.0f/(1.0f+expf(-x)); }
__device__ __forceinline__ unsigned short f2bf(float f){
    __hip_bfloat16 h = __float2bfloat16(f);   // RNE
    unsigned short s; __builtin_memcpy(&s,&h,2); return s;
}
__device__ __forceinline__ float bf2f(unsigned short u){
    unsigned int x = ((unsigned int)u)<<16; float f; __builtin_memcpy(&f,&x,4); return f;
}

// ---------- pre-pass: transpose+convert W [rows][2048] fp32 -> out[c][koff+k] bf16 ----------
__global__ __launch_bounds__(256) void wtrans(const float* __restrict__ in, int rows,
                                              unsigned short* __restrict__ out,
                                              int Kout, int koff) {
    __shared__ float tl[32][33];
    int tx = threadIdx.x, ty = threadIdx.y;
    int c0 = blockIdx.x * 32, k0 = blockIdx.y * 32;
    #pragma unroll
    for (int i = 0; i < 4; i++)
        tl[ty + i * 8][tx] = in[(size_t)(k0 + ty + i * 8) * G4 + c0 + tx];
    __syncthreads();
    #pragma unroll
    for (int i = 0; i < 4; i++)
        out[(size_t)(c0 + ty + i * 8) * Kout + koff + k0 + tx] = f2bf(tl[tx][ty + i * 8]);
}

// ---------- pre-pass: gather embeddings -> xbf[t][b][k] bf16 ----------
__global__ __launch_bounds__(64) void xgather(const int* __restrict__ tokens,
                                              const float* __restrict__ emb,
                                              unsigned short* __restrict__ xbf) {
    int flat = blockIdx.x;
    int b = flat & 255, t = flat >> 8;
    int tok = tokens[b * TT + t];
    float4 v = ((const float4*)(emb + (size_t)tok * EE))[threadIdx.x];
    ushort4 o;
    o.x = f2bf(v.x); o.y = f2bf(v.y); o.z = f2bf(v.z); o.w = f2bf(v.w);
    ((ushort4*)(xbf + ((size_t)t * BB + b) * EE))[threadIdx.x] = o;
}

// ---------- one LSTM timestep: HARDWARE (kernel-boundary) sync ----------
// Dataflow reordered so kernel(p) has NO intra-kernel dependency:
//   blocks 0..127  (L0): h0(p+1) <- h0(p), x(p)          [skip at p==TT]
//   blocks 128..255(L1): h1(p)   <- h0(p), h1(p-1)        [skip at p==0]
// Both inputs were written by kernel(p-1) -> the stream/graph edge provides
// ordering AND cross-XCD coherence; all h/c traffic is PLAIN loads/stores
// (no atomics, flags, polls, fences). c-state lives in fp32 global buffers
// (exact roundtrip). Arithmetic (fragment map, kt order, gating) is copied
// byte-for-byte from the R4/R8 champion -> absmax 0.0 expected.
// Per block: 64 batch rows x 16 units, 4 waves (16 rows each), weights
// staged to LDS lane-ordered (conflict-free, R3-proven) each step.
__global__ __launch_bounds__(256, 1) void lstm_step(
    int p,
    const unsigned short* __restrict__ Wt0,   // [2048][768]  bf16 [col][k]
    const unsigned short* __restrict__ Wt1,   // [2048][1024]
    const unsigned short* __restrict__ xbf,   // [256][256][256] bf16 (or unused)
    const int* __restrict__ tokens, const float* __restrict__ emb,
    const float* __restrict__ b0v, const float* __restrict__ b1v,
    unsigned short* __restrict__ h0buf,       // [2][256][512] bf16
    unsigned short* __restrict__ h1buf,       // [2][256][512] bf16
    float* __restrict__ c0buf,                // [256][512] fp32
    float* __restrict__ c1buf,                // [256][512] fp32
    int use_xbf)
{
    extern __shared__ char smem[];
    unsigned short* wl  = (unsigned short*)smem;               // lane-ordered weights (<=128KB)
    unsigned short* hst = (unsigned short*)(smem + 131072);    // 64x16 h staging, stride 24 (3KB)
    int*            tokl = (int*)(smem + 131072 + 3072);       // 64 ints

    const int tid   = threadIdx.x;
    const int bid   = blockIdx.x;
    const int layer = bid >> 7;
    if (layer == 0) { if (p >= TT) return; }
    else            { if (p < 1)   return; }
    const int lb    = bid & 127;
    const int g     = lb >> 5;
    const int u0    = (lb & 31) * 16;
    const int row0  = g * 64;
    const int K     = layer ? 1024 : 768;
    const int KT    = K / 32;                  // 24 or 32 k-tiles
    const unsigned short* Wt = layer ? Wt1 : Wt0;
    const float* bR = layer ? b1v : b0v;
    float* cb = layer ? c1buf : c0buf;

    // ---- stage weights, LANE-ordered chunks: i = ((gate*KT+kt)*64 + (q*16+n)) ----
    const int nch = 4 * KT * 64;
    for (int i = tid; i < nch; i += 256) {
        int n  = i & 15;
        int q2 = (i >> 4) & 3;
        int t2 = i >> 6;
        int kt = t2 % KT, gate = t2 / KT;
        const unsigned short* src = Wt + (size_t)(gate * UU + u0 + n) * K + kt * 32 + q2 * 8;
        *(short8*)(wl + (size_t)i * 8) = *(const short8*)src;
    }
    if (layer == 0 && !use_xbf && tid < 64)
        tokl[tid] = tokens[(size_t)(row0 + tid) * TT + p];
    __syncthreads();   // wl (and tokl) ready

    const int lane = tid & 63;
    const int w    = tid >> 6;
    const int n16  = lane & 15;
    const int q    = lane >> 4;
    const int q8   = q * 8;
    const int myrow = row0 + w * 16 + n16;
    const unsigned short* wlane = wl + lane * 8;   // + (gate*KT+kt)*512 shorts

    float gb[4];
    #pragma unroll
    for (int gate = 0; gate < 4; gate++) gb[gate] = bR[gate * UU + u0 + (tid & 15)];

    // c-state for this thread: rows row0+w*16+q*4+r, col u0+n16 (fp32 exact)
    float cst[4];
    #pragma unroll
    for (int r = 0; r < 4; r++)
        cst[r] = cb[(size_t)(row0 + w * 16 + q * 4 + r) * UU + u0 + n16];

    f32x4 acc[4];
    #pragma unroll
    for (int gate = 0; gate < 4; gate++)
        acc[gate] = (f32x4){gb[gate], gb[gate], gb[gate], gb[gate]};

    const size_t HS = (size_t)BB * UU;
    unsigned short* hw;

    if (layer == 0) {
        const unsigned short* h0r = h0buf + (size_t)(p & 1) * HS;      // h0(p)
        hw = h0buf + (size_t)((p + 1) & 1) * HS;                       // h0(p+1)

        // ---- x part (kt 0..7) ----
        if (!use_xbf) {
            const float* ep = emb + (size_t)tokl[w * 16 + n16] * EE + q8;
            #pragma unroll
            for (int kt = 0; kt < 8; kt++) {
                float4 f0 = *(const float4*)(ep + kt * 32);
                float4 f1 = *(const float4*)(ep + kt * 32 + 4);
                union { unsigned short s[8]; short8 v; } u;
                u.s[0]=f2bf(f0.x); u.s[1]=f2bf(f0.y); u.s[2]=f2bf(f0.z); u.s[3]=f2bf(f0.w);
                u.s[4]=f2bf(f1.x); u.s[5]=f2bf(f1.y); u.s[6]=f2bf(f1.z); u.s[7]=f2bf(f1.w);
                #pragma unroll
                for (int gate = 0; gate < 4; gate++) {
                    short8 bv = *(const short8*)(wlane + (size_t)(gate * KT + kt) * 512);
                    acc[gate] = __builtin_amdgcn_mfma_f32_16x16x32_bf16(u.v, bv, acc[gate], 0, 0, 0);
                }
            }
        } else {
            const unsigned short* xp = xbf + ((size_t)p * BB + myrow) * EE + q8;
            #pragma unroll
            for (int kt = 0; kt < 8; kt++) {
                short8 av = *(const short8*)(xp + kt * 32);
                #pragma unroll
                for (int gate = 0; gate < 4; gate++) {
                    short8 bv = *(const short8*)(wlane + (size_t)(gate * KT + kt) * 512);
                    acc[gate] = __builtin_amdgcn_mfma_f32_16x16x32_bf16(av, bv, acc[gate], 0, 0, 0);
                }
            }
        }

        // ---- h part (kt 8..23), 2-stage register pipeline, PLAIN loads ----
        const unsigned short* ah = h0r + (size_t)myrow * UU + q8;
        short8 ab[2][8];
        #pragma unroll
        for (int i = 0; i < 8; i++) ab[0][i] = *(const short8*)(ah + i * 32);   // kt 8..15
        #pragma unroll
        for (int s = 0; s < 2; s++) {
            const int cur = s & 1, nxt = cur ^ 1;
            if (s < 1) {
                #pragma unroll
                for (int i = 0; i < 8; i++)
                    ab[nxt][i] = *(const short8*)(ah + (8 + i) * 32);           // kt 16..23
            }
            #pragma unroll
            for (int i = 0; i < 8; i++) {
                int kt = 8 + s * 8 + i;
                short8 av = ab[cur][i];
                #pragma unroll
                for (int gate = 0; gate < 4; gate++) {
                    short8 bv = *(const short8*)(wlane + (size_t)(gate * KT + kt) * 512);
                    acc[gate] = __builtin_amdgcn_mfma_f32_16x16x32_bf16(av, bv, acc[gate], 0, 0, 0);
                }
            }
        }
    } else {
        const unsigned short* h0r = h0buf + (size_t)(p & 1) * HS;        // h0(p)
        const unsigned short* h1r = h1buf + (size_t)((p + 1) & 1) * HS;  // h1(p-1)
        hw = h1buf + (size_t)(p & 1) * HS;                               // h1(p)
        const unsigned short* a0 = h0r + (size_t)myrow * UU + q8;
        const unsigned short* a1 = h1r + (size_t)myrow * UU + q8;
        short8 ab[2][8];
        #pragma unroll
        for (int i = 0; i < 8; i++) ab[0][i] = *(const short8*)(a0 + i * 32);   // kt 0..7
        #pragma unroll
        for (int s = 0; s < 4; s++) {
            const int cur = s & 1, nxt = cur ^ 1;
            if (s < 3) {
                #pragma unroll
                for (int i = 0; i < 8; i++) {
                    int kt = (s + 1) * 8 + i;
                    const unsigned short* ap = (kt < 16) ? (a0 + kt * 32)
                                                         : (a1 + (kt - 16) * 32);
                    ab[nxt][i] = *(const short8*)ap;
                }
            }
            #pragma unroll
            for (int i = 0; i < 8; i++) {
                int kt = s * 8 + i;
                short8 av = ab[cur][i];
                #pragma unroll
                for (int gate = 0; gate < 4; gate++) {
                    short8 bv = *(const short8*)(wlane + (size_t)(gate * KT + kt) * 512);
                    acc[gate] = __builtin_amdgcn_mfma_f32_16x16x32_bf16(av, bv, acc[gate], 0, 0, 0);
                }
            }
        }
    }

    // ---- gating (D layout: col=n16 -> u, row=q*4+r); c writeback; h staging ----
    #pragma unroll
    for (int r = 0; r < 4; r++) {
        float zi = acc[0][r];
        float zf = acc[1][r];
        float zg = acc[2][r];
        float zo = acc[3][r];
        float cn = sigf(zf) * cst[r] + sigf(zi) * tanhf(zg);
        cb[(size_t)(row0 + w * 16 + q * 4 + r) * UU + u0 + n16] = cn;
        hst[(w * 16 + q * 4 + r) * 24 + n16] = f2bf(sigf(zo) * tanhf(cn));
    }
    __syncthreads();   // hst complete
    if (tid < 128) {   // coalesced PLAIN store: 128 threads x 16B
        int row = tid >> 1, half = tid & 1;
        const unsigned long long* s = (const unsigned long long*)(hst + row * 24 + half * 8);
        unsigned long long* dp = (unsigned long long*)(hw + (size_t)(row0 + row) * UU + u0 + half * 8);
        dp[0] = s[0];
        dp[1] = s[1];
    }
}

// ---------- final dense: out[b] = sigmoid(h1 . Wd + bd) ----------
__global__ __launch_bounds__(64) void dense_out(
    const unsigned short* __restrict__ h, const float* __restrict__ Wd,
    const float* __restrict__ bd, float* __restrict__ out)
{
    int b = blockIdx.x;
    int lane = threadIdx.x;
    float s = 0.f;
    #pragma unroll
    for (int k = lane; k < UU; k += 64) s += bf2f(h[(size_t)b * UU + k]) * Wd[k];
    #pragma unroll
    for (int off = 32; off > 0; off >>= 1) s += __shfl_down(s, off);
    if (lane == 0) out[b] = sigf(s + bd[0]);
}

extern "C" void kernel_launch(void* const* d_in, const int* in_sizes, int n_in,
                              void* d_out, int out_size, void* d_ws, size_t ws_size,
                              hipStream_t stream) {
    const int*   tokens = (const int*)  d_in[0];
    const float* emb    = (const float*)d_in[1];
    const float* W0     = (const float*)d_in[2];
    const float* U0     = (const float*)d_in[3];
    const float* b0     = (const float*)d_in[4];
    const float* W1     = (const float*)d_in[5];
    const float* U1     = (const float*)d_in[6];
    const float* b1     = (const float*)d_in[7];
    const float* Wd     = (const float*)d_in[8];
    const float* bd     = (const float*)d_in[9];
    float* out = (float*)d_out;

    // ws layout (bytes):
    // [Wt0 3MB][Wt1 4MB][h0 x2 0.5MB][h1 x2 0.5MB][c0 0.5MB][c1 0.5MB][xbf 32MB]
    const size_t oWt0 = 0;
    const size_t oWt1 = (size_t)G4 * 768 * 2;                 // 3,145,728
    const size_t oH0  = oWt1 + (size_t)G4 * 1024 * 2;         // 7,340,032
    const size_t oH1  = oH0 + (size_t)2 * BB * UU * 2;        // +524,288
    const size_t oC0  = oH1 + (size_t)2 * BB * UU * 2;        // +524,288
    const size_t oC1  = oC0 + (size_t)BB * UU * 4;            // +524,288
    const size_t oX   = oC1 + (size_t)BB * UU * 4;            // +524,288
    const size_t needFull = oX + (size_t)TT * BB * EE * 2;    // ~43.0 MB
    int use_xbf = (ws_size >= needFull) ? 1 : 0;

    unsigned short* Wt0p = (unsigned short*)((char*)d_ws + oWt0);
    unsigned short* Wt1p = (unsigned short*)((char*)d_ws + oWt1);
    unsigned short* h0p  = (unsigned short*)((char*)d_ws + oH0);
    unsigned short* h1p  = (unsigned short*)((char*)d_ws + oH1);
    float*          c0p  = (float*)        ((char*)d_ws + oC0);
    float*          c1p  = (float*)        ((char*)d_ws + oC1);
    unsigned short* xbfp = (unsigned short*)((char*)d_ws + oX);

    hipMemsetAsync((char*)d_ws + oH0, 0, oX - oH0, stream);   // h0,h1,c0,c1 = 0

    wtrans<<<dim3(G4 / 32, EE / 32), dim3(32, 8), 0, stream>>>(W0, EE, Wt0p, 768, 0);
    wtrans<<<dim3(G4 / 32, UU / 32), dim3(32, 8), 0, stream>>>(U0, UU, Wt0p, 768, 256);
    wtrans<<<dim3(G4 / 32, UU / 32), dim3(32, 8), 0, stream>>>(W1, UU, Wt1p, 1024, 0);
    wtrans<<<dim3(G4 / 32, UU / 32), dim3(32, 8), 0, stream>>>(U1, UU, Wt1p, 1024, 512);

    if (use_xbf)
        xgather<<<dim3(BB * TT), dim3(64), 0, stream>>>(tokens, emb, xbfp);

    {
        const size_t shmem = 131072 + 3072 + 256;   // wl + hst + tokl
        hipFuncSetAttribute((const void*)lstm_step,
                            hipFuncAttributeMaxDynamicSharedMemorySize, (int)shmem);
        for (int p = 0; p <= TT; p++) {
            lstm_step<<<dim3(256), dim3(256), shmem, stream>>>(
                p, Wt0p, Wt1p, xbfp, tokens, emb, b0, b1,
                h0p, h1p, c0p, c1p, use_xbf);
        }
    }

    dense_out<<<dim3(BB), dim3(64), 0, stream>>>(h1p, Wd, bd, out);   // h1(256) = slot 0
}

// Round 10
// 2608.619 us; speedup vs baseline: 1.6277x; 1.6277x over previous
//
#include <hip/hip_runtime.h>
#include <hip/hip_bf16.h>
#include <math.h>

#define VB 50000
#define EE 256
#define UU 512
#define BB 256
#define TT 256
#define G4 2048

typedef __attribute__((ext_vector_type(8))) short short8;
typedef __attribute__((ext_vector_type(2))) unsigned long long u64x2;
typedef __attribute__((ext_vector_type(4))) float f32x4;

__device__ __forceinline__ float sigf(float x){ return 1.0f/(1.0f+expf(-x)); }
__device__ __forceinline__ unsigned short f2bf(float f){
    __hip_bfloat16 h = __float2bfloat16(f);   // RNE
    unsigned short s; __builtin_memcpy(&s,&h,2); return s;
}
__device__ __forceinline__ float bf2f(unsigned short u){
    unsigned int x = ((unsigned int)u)<<16; float f; __builtin_memcpy(&f,&x,4); return f;
}

// agent-scope flag ops (4B, via __hip_atomic: compiler emits sc1 forms)
__device__ __forceinline__ unsigned int cldu(const unsigned int* p){
    return __hip_atomic_load(p, __ATOMIC_RELAXED, __HIP_MEMORY_SCOPE_AGENT);
}
__device__ __forceinline__ void cstu(unsigned int* p, unsigned int v){
    __hip_atomic_store(p, v, __ATOMIC_RELAXED, __HIP_MEMORY_SCOPE_AGENT);
}

// 16B agent-scope coherent LOAD: sc1 = agent bit (same scope the compiler
// emits for the 8B __hip_atomic loads), but ONE transaction instead of two.
// NO waitcnt inside -- caller must `s_waitcnt vmcnt(0)` + sched_barrier(0)
// before first use (rule #18: compiler hoists reg-only MFMA past asm waits).
__device__ __forceinline__ short8 cld16w(const unsigned short* p){
    short8 v;
    asm volatile("global_load_dwordx4 %0, %1, off sc1"
                 : "=&v"(v) : "v"(p));
    return v;
}
// 16B agent-scope coherent STORE (one transaction instead of two 8B).
__device__ __forceinline__ void cst16w(unsigned long long* dp, u64x2 v){
    asm volatile("global_store_dwordx4 %0, %1, off sc1"
                 :: "v"(dp), "v"(v) : "memory");
}

// ---------- pre-pass: transpose+convert W [rows][2048] fp32 -> out[c][koff+k] bf16 ----------
__global__ __launch_bounds__(256) void wtrans(const float* __restrict__ in, int rows,
                                              unsigned short* __restrict__ out,
                                              int Kout, int koff) {
    __shared__ float tl[32][33];
    int tx = threadIdx.x, ty = threadIdx.y;
    int c0 = blockIdx.x * 32, k0 = blockIdx.y * 32;
    #pragma unroll
    for (int i = 0; i < 4; i++)
        tl[ty + i * 8][tx] = in[(size_t)(k0 + ty + i * 8) * G4 + c0 + tx];
    __syncthreads();
    #pragma unroll
    for (int i = 0; i < 4; i++)
        out[(size_t)(c0 + ty + i * 8) * Kout + koff + k0 + tx] = f2bf(tl[tx][ty + i * 8]);
}

// ---------- pre-pass: gather embeddings -> xbf[t][b][k] bf16 ----------
__global__ __launch_bounds__(64) void xgather(const int* __restrict__ tokens,
                                              const float* __restrict__ emb,
                                              unsigned short* __restrict__ xbf) {
    int flat = blockIdx.x;
    int b = flat & 255, t = flat >> 8;
    int tok = tokens[b * TT + t];
    float4 v = ((const float4*)(emb + (size_t)tok * EE))[threadIdx.x];
    ushort4 o;
    o.x = f2bf(v.x); o.y = f2bf(v.y); o.z = f2bf(v.z); o.w = f2bf(v.w);
    ((ushort4*)(xbf + ((size_t)t * BB + b) * EE))[threadIdx.x] = o;
}

// ---------- persistent 2-layer LSTM ----------
// STRUCTURE/PROTOCOL = round-8 champion verbatim (3008us, absmax 0.0):
//   4 groups x 64 blocks; single-wave poll + barrier release; lane-ordered
//   LDS weights; hst staging + coalesced stores; flags at 4B stride.
// ONE change: all coherent h traffic widened 8B -> 16B transactions
// (global_load/store_dwordx4 sc1 inline asm). Theory: per-step time is
// bound by coherent-point TRANSACTION RATE (~3.1M 8B transactions/step =
// 266G/s at 11.8us/step); R7 added transactions -> proportionally slower,
// R3/R4/R8 (count-neutral) -> flat. Halving the count is the direct test.
// MFMA order and gating byte-identical -> absmax 0.0 expected.
__global__ __launch_bounds__(256, 1) void rnn_persist(
    const unsigned short* __restrict__ Wt0,   // [2048][768]  bf16 [col][k]
    const unsigned short* __restrict__ Wt1,   // [2048][1024]
    const unsigned short* __restrict__ xbf,   // [256][256][256] bf16 (or unused)
    const int* __restrict__ tokens, const float* __restrict__ emb,
    const float* __restrict__ b0v, const float* __restrict__ b1v,
    unsigned short* __restrict__ h0buf,       // [4][256][512] bf16 ring
    unsigned short* __restrict__ h1buf,       // [2][256][512] bf16 ring
    unsigned int* __restrict__ bars,          // per group 1024 uints (4KB)
    int use_xbf)
{
    extern __shared__ char smem[];
    unsigned short* wl  = (unsigned short*)smem;               // lane-ordered weights (<=128KB)
    unsigned short* hst = (unsigned short*)(smem + 131072);    // 64x16 h staging, stride 24 (3KB)
    int*            tokl = (int*)(smem + 131072 + 3072);       // 64 ints

    const int tid   = threadIdx.x;
    const int bid   = blockIdx.x;
    const int g     = bid >> 6;
    const int local = bid & 63;
    const int layer = local >> 5;
    const int u0    = (local & 31) * 16;
    const int row0  = g * 64;
    const int K     = layer ? 1024 : 768;
    const int KT    = K / 32;                  // 24 or 32 k-tiles
    const unsigned short* Wt = layer ? Wt1 : Wt0;
    const float* bR = layer ? b1v : b0v;

    // ---- fill LDS weights, LANE-ordered chunks: i = ((gate*KT+kt)*64 + (q*16+n)) ----
    const int nch = 4 * KT * 64;
    for (int i = tid; i < nch; i += 256) {
        int n  = i & 15;
        int q2 = (i >> 4) & 3;
        int t2 = i >> 6;
        int kt = t2 % KT, gate = t2 / KT;
        const unsigned short* src = Wt + (size_t)(gate * UU + u0 + n) * K + kt * 32 + q2 * 8;
        *(short8*)(wl + (size_t)i * 8) = *(const short8*)src;
    }

    float gb[4];
    #pragma unroll
    for (int gate = 0; gate < 4; gate++) gb[gate] = bR[gate * UU + u0 + (tid & 15)];
    float cst[4] = {0.f, 0.f, 0.f, 0.f};

    const int lane = tid & 63;
    const int w    = tid >> 6;
    const int n16  = lane & 15;
    const int q    = lane >> 4;
    const int q8   = q * 8;
    const int myrow = row0 + w * 16 + n16;
    const unsigned short* wlane = wl + lane * 8;   // + (gate*KT+kt)*512 shorts

    // flag region for this group: flag(local) at 4B stride
    unsigned int* flg = bars + (size_t)g * 1024;
    unsigned int* myFlag = flg + local;
    // poller (wave 0 only): lane L polls flag of block L
    const unsigned int* pollp = flg + lane;
    const int pollSlack = (layer == 0 && lane >= 32) ? 2 : 0;  // L0 waits L1>=p-2

    const size_t HS = (size_t)BB * UU;

    __syncthreads();   // wl ready

    for (int p = 0; p <= TT; p++) {
        const bool active = layer ? (p >= 1) : (p < TT);
        const bool wait_needed = layer ? (p >= 1) : (p < TT);

        f32x4 acc[4];
        #pragma unroll
        for (int gate = 0; gate < 4; gate++)
            acc[gate] = (f32x4){gb[gate], gb[gate], gb[gate], gb[gate]};

        // ---- L0 x-part precompute (static inputs only) BEFORE the wait ----
        if (layer == 0 && p < TT) {
            if (!use_xbf) {
                if (tid < 64) tokl[tid] = tokens[(size_t)(row0 + tid) * TT + p];
                __syncthreads();
                const float* ep = emb + (size_t)tokl[w * 16 + n16] * EE + q8;
                #pragma unroll
                for (int kt = 0; kt < 8; kt++) {
                    float4 f0 = *(const float4*)(ep + kt * 32);
                    float4 f1 = *(const float4*)(ep + kt * 32 + 4);
                    union { unsigned short s[8]; short8 v; } u;
                    u.s[0]=f2bf(f0.x); u.s[1]=f2bf(f0.y); u.s[2]=f2bf(f0.z); u.s[3]=f2bf(f0.w);
                    u.s[4]=f2bf(f1.x); u.s[5]=f2bf(f1.y); u.s[6]=f2bf(f1.z); u.s[7]=f2bf(f1.w);
                    #pragma unroll
                    for (int gate = 0; gate < 4; gate++) {
                        short8 bv = *(const short8*)(wlane + (size_t)(gate * KT + kt) * 512);
                        acc[gate] = __builtin_amdgcn_mfma_f32_16x16x32_bf16(u.v, bv, acc[gate], 0, 0, 0);
                    }
                }
            } else {
                const unsigned short* xp = xbf + ((size_t)p * BB + myrow) * EE + q8;
                #pragma unroll
                for (int kt = 0; kt < 8; kt++) {
                    short8 av = *(const short8*)(xp + kt * 32);
                    #pragma unroll
                    for (int gate = 0; gate < 4; gate++) {
                        short8 bv = *(const short8*)(wlane + (size_t)(gate * KT + kt) * 512);
                        acc[gate] = __builtin_amdgcn_mfma_f32_16x16x32_bf16(av, bv, acc[gate], 0, 0, 0);
                    }
                }
            }
        }

        // ---- SINGLE-WAVE poll (wave 0: lane L -> flag L), barrier release ----
        if (wait_needed) {
            if (tid < 64) {
                const int thr = p - pollSlack;
                for (;;) {
                    bool bad = ((int)cldu(pollp) < thr);
                    if (__ballot(bad) == 0ULL) break;
                    __builtin_amdgcn_s_sleep(1);
                }
            }
            __syncthreads();
        }

        // ---- dynamic (h-dependent) part: 16B coherent loads, full issue ----
        if (active) {
            const unsigned short* h0r = h0buf + (size_t)(p & 3) * HS;
            unsigned short* hw;

            if (layer) {
                const unsigned short* h1r = h1buf + (size_t)((p + 1) & 1) * HS;  // h1(p-1)
                hw = h1buf + (size_t)(p & 1) * HS;
                const unsigned short* a0 = h0r + (size_t)myrow * UU + q8;
                const unsigned short* a1 = h1r + (size_t)myrow * UU + q8;
                short8 ha[16], hc[16];
                #pragma unroll
                for (int i = 0; i < 16; i++) ha[i] = cld16w(a0 + i * 32);   // kt 0..15
                #pragma unroll
                for (int i = 0; i < 16; i++) hc[i] = cld16w(a1 + i * 32);   // kt 16..31
                asm volatile("s_waitcnt vmcnt(0)" ::: "memory");
                __builtin_amdgcn_sched_barrier(0);
                #pragma unroll
                for (int i = 0; i < 16; i++) {
                    #pragma unroll
                    for (int gate = 0; gate < 4; gate++) {
                        short8 bv = *(const short8*)(wlane + (size_t)(gate * KT + i) * 512);
                        acc[gate] = __builtin_amdgcn_mfma_f32_16x16x32_bf16(ha[i], bv, acc[gate], 0, 0, 0);
                    }
                }
                #pragma unroll
                for (int i = 0; i < 16; i++) {
                    #pragma unroll
                    for (int gate = 0; gate < 4; gate++) {
                        short8 bv = *(const short8*)(wlane + (size_t)(gate * KT + 16 + i) * 512);
                        acc[gate] = __builtin_amdgcn_mfma_f32_16x16x32_bf16(hc[i], bv, acc[gate], 0, 0, 0);
                    }
                }
            } else {
                hw = h0buf + (size_t)((p + 1) & 3) * HS;
                const unsigned short* ah = h0r + (size_t)myrow * UU + q8;
                short8 hb[16];
                #pragma unroll
                for (int i = 0; i < 16; i++) hb[i] = cld16w(ah + i * 32);   // kt 8..23
                asm volatile("s_waitcnt vmcnt(0)" ::: "memory");
                __builtin_amdgcn_sched_barrier(0);
                #pragma unroll
                for (int i = 0; i < 16; i++) {
                    #pragma unroll
                    for (int gate = 0; gate < 4; gate++) {
                        short8 bv = *(const short8*)(wlane + (size_t)(gate * KT + 8 + i) * 512);
                        acc[gate] = __builtin_amdgcn_mfma_f32_16x16x32_bf16(hb[i], bv, acc[gate], 0, 0, 0);
                    }
                }
            }

            // gating (D layout: col=n16 -> u, row=q*4+r); stage h to LDS (stride 24)
            #pragma unroll
            for (int r = 0; r < 4; r++) {
                float zi = acc[0][r];
                float zf = acc[1][r];
                float zg = acc[2][r];
                float zo = acc[3][r];
                float cn = sigf(zf) * cst[r] + sigf(zi) * tanhf(zg);
                cst[r] = cn;
                hst[(w * 16 + q * 4 + r) * 24 + n16] = f2bf(sigf(zo) * tanhf(cn));
            }
            __syncthreads();   // hst complete (block-uniform path)
            if (tid < 128) {   // coalesced coherent store: 128 threads x ONE 16B
                int row = tid >> 1, half = tid & 1;
                u64x2 sv = *(const u64x2*)(hst + row * 24 + half * 8);
                unsigned long long* dp = (unsigned long long*)
                    (hw + (size_t)(row0 + row) * UU + u0 + half * 8);
                cst16w(dp, sv);
            }
        }

        // ---- arrive(p): every wave drains its own vmem, then tid0 flags ----
        if (p < TT) {
            asm volatile("s_waitcnt vmcnt(0)" ::: "memory");
            __syncthreads();
            if (tid == 0) cstu(myFlag, (unsigned int)(p + 1));
        }
    }
}

// ---------- final dense: out[b] = sigmoid(h1 . Wd + bd) ----------
__global__ __launch_bounds__(64) void dense_out(
    const unsigned short* __restrict__ h, const float* __restrict__ Wd,
    const float* __restrict__ bd, float* __restrict__ out)
{
    int b = blockIdx.x;
    int lane = threadIdx.x;
    float s = 0.f;
    #pragma unroll
    for (int k = lane; k < UU; k += 64) s += bf2f(h[(size_t)b * UU + k]) * Wd[k];
    #pragma unroll
    for (int off = 32; off > 0; off >>= 1) s += __shfl_down(s, off);
    if (lane == 0) out[b] = sigf(s + bd[0]);
}

extern "C" void kernel_launch(void* const* d_in, const int* in_sizes, int n_in,
                              void* d_out, int out_size, void* d_ws, size_t ws_size,
                              hipStream_t stream) {
    const int*   tokens = (const int*)  d_in[0];
    const float* emb    = (const float*)d_in[1];
    const float* W0     = (const float*)d_in[2];
    const float* U0     = (const float*)d_in[3];
    const float* b0     = (const float*)d_in[4];
    const float* W1     = (const float*)d_in[5];
    const float* U1     = (const float*)d_in[6];
    const float* b1     = (const float*)d_in[7];
    const float* Wd     = (const float*)d_in[8];
    const float* bd     = (const float*)d_in[9];
    float* out = (float*)d_out;

    // ws layout (bytes):
    // [Wt0 3MB][Wt1 4MB][h0 ring x4 1MB][h1 ring x2 0.5MB][bars 32KB][xbf 32MB]
    const size_t oWt0 = 0;
    const size_t oWt1 = (size_t)G4 * 768 * 2;                 // 3,145,728
    const size_t oH0  = oWt1 + (size_t)G4 * 1024 * 2;         // 7,340,032
    const size_t oH1  = oH0 + (size_t)4 * BB * UU * 2;        // +1,048,576
    const size_t oBar = oH1 + (size_t)2 * BB * UU * 2;        // +524,288
    const size_t oX   = oBar + 32768;
    const size_t needFull = oX + (size_t)TT * BB * EE * 2;    // ~42.5 MB
    int use_xbf = (ws_size >= needFull) ? 1 : 0;

    unsigned short* Wt0p = (unsigned short*)((char*)d_ws + oWt0);
    unsigned short* Wt1p = (unsigned short*)((char*)d_ws + oWt1);
    unsigned short* h0p  = (unsigned short*)((char*)d_ws + oH0);
    unsigned short* h1p  = (unsigned short*)((char*)d_ws + oH1);
    unsigned int*   barp = (unsigned int*)  ((char*)d_ws + oBar);
    unsigned short* xbfp = (unsigned short*)((char*)d_ws + oX);

    hipMemsetAsync((char*)d_ws + oH0, 0, oX - oH0, stream);

    wtrans<<<dim3(G4 / 32, EE / 32), dim3(32, 8), 0, stream>>>(W0, EE, Wt0p, 768, 0);
    wtrans<<<dim3(G4 / 32, UU / 32), dim3(32, 8), 0, stream>>>(U0, UU, Wt0p, 768, 256);
    wtrans<<<dim3(G4 / 32, UU / 32), dim3(32, 8), 0, stream>>>(W1, UU, Wt1p, 1024, 0);
    wtrans<<<dim3(G4 / 32, UU / 32), dim3(32, 8), 0, stream>>>(U1, UU, Wt1p, 1024, 512);

    if (use_xbf)
        xgather<<<dim3(BB * TT), dim3(64), 0, stream>>>(tokens, emb, xbfp);

    {
        const size_t shmem = 131072 + 3072 + 256;   // wl + hst + tokl
        hipFuncSetAttribute((const void*)rnn_persist,
                            hipFuncAttributeMaxDynamicSharedMemorySize, (int)shmem);
        void* args[] = {(void*)&Wt0p, (void*)&Wt1p, (void*)&xbfp,
                        (void*)&tokens, (void*)&emb, (void*)&b0, (void*)&b1,
                        (void*)&h0p, (void*)&h1p, (void*)&barp, (void*)&use_xbf};
        hipLaunchCooperativeKernel((const void*)rnn_persist, dim3(256), dim3(256),
                                   args, shmem, stream);
    }

    dense_out<<<dim3(BB), dim3(64), 0, stream>>>(h1p, Wd, bd, out);   // h1(256) = slot 0
}

// Round 11
// 1971.610 us; speedup vs baseline: 2.1536x; 1.3231x over previous
//
#include <hip/hip_runtime.h>
#include <hip/hip_bf16.h>
#include <math.h>

#define VB 50000
#define EE 256
#define UU 512
#define BB 256
#define TT 256
#define G4 2048

typedef __attribute__((ext_vector_type(8))) short short8;
typedef __attribute__((ext_vector_type(2))) unsigned long long u64x2;
typedef __attribute__((ext_vector_type(4))) float f32x4;

__device__ __forceinline__ float sigf(float x){ return 1.0f/(1.0f+expf(-x)); }
__device__ __forceinline__ unsigned short f2bf(float f){
    __hip_bfloat16 h = __float2bfloat16(f);   // RNE
    unsigned short s; __builtin_memcpy(&s,&h,2); return s;
}
__device__ __forceinline__ float bf2f(unsigned short u){
    unsigned int x = ((unsigned int)u)<<16; float f; __builtin_memcpy(&f,&x,4); return f;
}

// agent-scope flag ops (4B)
__device__ __forceinline__ unsigned int cldu(const unsigned int* p){
    return __hip_atomic_load(p, __ATOMIC_RELAXED, __HIP_MEMORY_SCOPE_AGENT);
}
__device__ __forceinline__ void cstu(unsigned int* p, unsigned int v){
    __hip_atomic_store(p, v, __ATOMIC_RELAXED, __HIP_MEMORY_SCOPE_AGENT);
}

// 16B agent-scope coherent LOAD (sc1): ONE transaction. NO waitcnt inside --
// caller must s_waitcnt vmcnt(N) + sched_barrier(0) before first use.
__device__ __forceinline__ short8 cld16w(const unsigned short* p){
    short8 v;
    asm volatile("global_load_dwordx4 %0, %1, off sc1"
                 : "=&v"(v) : "v"(p));
    return v;
}
// 16B agent-scope coherent STORE (one transaction).
__device__ __forceinline__ void cst16w(unsigned long long* dp, u64x2 v){
    asm volatile("global_store_dwordx4 %0, %1, off sc1"
                 :: "v"(dp), "v"(v) : "memory");
}

// ---------- pre-pass: transpose+convert W [rows][2048] fp32 -> out[c][koff+k] bf16 ----------
__global__ __launch_bounds__(256) void wtrans(const float* __restrict__ in, int rows,
                                              unsigned short* __restrict__ out,
                                              int Kout, int koff) {
    __shared__ float tl[32][33];
    int tx = threadIdx.x, ty = threadIdx.y;
    int c0 = blockIdx.x * 32, k0 = blockIdx.y * 32;
    #pragma unroll
    for (int i = 0; i < 4; i++)
        tl[ty + i * 8][tx] = in[(size_t)(k0 + ty + i * 8) * G4 + c0 + tx];
    __syncthreads();
    #pragma unroll
    for (int i = 0; i < 4; i++)
        out[(size_t)(c0 + ty + i * 8) * Kout + koff + k0 + tx] = f2bf(tl[tx][ty + i * 8]);
}

// ---------- pre-pass: gather embeddings -> xbf[t][b][k] bf16 ----------
__global__ __launch_bounds__(64) void xgather(const int* __restrict__ tokens,
                                              const float* __restrict__ emb,
                                              unsigned short* __restrict__ xbf) {
    int flat = blockIdx.x;
    int b = flat & 255, t = flat >> 8;
    int tok = tokens[b * TT + t];
    float4 v = ((const float4*)(emb + (size_t)tok * EE))[threadIdx.x];
    ushort4 o;
    o.x = f2bf(v.x); o.y = f2bf(v.y); o.z = f2bf(v.z); o.w = f2bf(v.w);
    ((ushort4*)(xbf + ((size_t)t * BB + b) * EE))[threadIdx.x] = o;
}

// ---------- persistent 2-layer LSTM ----------
// BASE = round-10 champion (2549us): 16B sc1 coherent h traffic, lane-ordered
// LDS weights, hst staging, flags at 4B stride.
// Changes this round (zero new transactions, post-flag path shortening):
//  1) L1 TWO-PHASE wait + counted vmcnt: wait L0-half flags -> issue h0 loads
//     -> wait L1-half flags (the binding one; h0 loads in flight) -> issue h1
//     loads -> vmcnt(16) -> h0 MFMAs -> vmcnt(0) -> h1 MFMAs. Removes h0 load
//     RT + h0 MFMAs from the post-h1-flag critical path; staggers the load
//     burst into two halves.
//  2) L0 (xbf): x-MFMAs moved AFTER h-load issue (before vmcnt(0)) -- they now
//     hide the h load RT. Accumulation order unchanged (x kt0..7 then h) ->
//     bit-identical to R10.
//  3) h0 ring 4->8 deep; L0's slack on L1 flags 2->6: L0 almost never waits
//     on L1, its period is its own chain only.
__global__ __launch_bounds__(256, 1) void rnn_persist(
    const unsigned short* __restrict__ Wt0,   // [2048][768]  bf16 [col][k]
    const unsigned short* __restrict__ Wt1,   // [2048][1024]
    const unsigned short* __restrict__ xbf,   // [256][256][256] bf16 (or unused)
    const int* __restrict__ tokens, const float* __restrict__ emb,
    const float* __restrict__ b0v, const float* __restrict__ b1v,
    unsigned short* __restrict__ h0buf,       // [8][256][512] bf16 ring
    unsigned short* __restrict__ h1buf,       // [2][256][512] bf16 ring
    unsigned int* __restrict__ bars,          // per group 1024 uints (4KB)
    int use_xbf)
{
    extern __shared__ char smem[];
    unsigned short* wl  = (unsigned short*)smem;               // lane-ordered weights (<=128KB)
    unsigned short* hst = (unsigned short*)(smem + 131072);    // 64x16 h staging, stride 24 (3KB)
    int*            tokl = (int*)(smem + 131072 + 3072);       // 64 ints

    const int tid   = threadIdx.x;
    const int bid   = blockIdx.x;
    const int g     = bid >> 6;
    const int local = bid & 63;
    const int layer = local >> 5;
    const int u0    = (local & 31) * 16;
    const int row0  = g * 64;
    const int K     = layer ? 1024 : 768;
    const int KT    = K / 32;                  // 24 or 32 k-tiles
    const unsigned short* Wt = layer ? Wt1 : Wt0;
    const float* bR = layer ? b1v : b0v;

    // ---- fill LDS weights, LANE-ordered chunks: i = ((gate*KT+kt)*64 + (q*16+n)) ----
    const int nch = 4 * KT * 64;
    for (int i = tid; i < nch; i += 256) {
        int n  = i & 15;
        int q2 = (i >> 4) & 3;
        int t2 = i >> 6;
        int kt = t2 % KT, gate = t2 / KT;
        const unsigned short* src = Wt + (size_t)(gate * UU + u0 + n) * K + kt * 32 + q2 * 8;
        *(short8*)(wl + (size_t)i * 8) = *(const short8*)src;
    }

    float gb[4];
    #pragma unroll
    for (int gate = 0; gate < 4; gate++) gb[gate] = bR[gate * UU + u0 + (tid & 15)];
    float cst[4] = {0.f, 0.f, 0.f, 0.f};

    const int lane = tid & 63;
    const int w    = tid >> 6;
    const int n16  = lane & 15;
    const int q    = lane >> 4;
    const int q8   = q * 8;
    const int myrow = row0 + w * 16 + n16;
    const unsigned short* wlane = wl + lane * 8;   // + (gate*KT+kt)*512 shorts

    // flag region for this group: flag(local) at 4B stride
    unsigned int* flg = bars + (size_t)g * 1024;
    unsigned int* myFlag = flg + local;
    // poll target: lane L polls flag of block L
    const unsigned int* pollp = flg + lane;
    const int pollSlack = (layer == 0 && lane >= 32) ? 6 : 0;  // L0 waits L1>=p-6 (ring 8)

    const size_t HS = (size_t)BB * UU;

    __syncthreads();   // wl ready

    for (int p = 0; p <= TT; p++) {
        const bool active = layer ? (p >= 1) : (p < TT);

        f32x4 acc[4];
        #pragma unroll
        for (int gate = 0; gate < 4; gate++)
            acc[gate] = (f32x4){gb[gate], gb[gate], gb[gate], gb[gate]};

        // ---- L0 x-part (static inputs) BEFORE the wait ----
        short8 xv[8];
        if (layer == 0 && p < TT) {
            if (!use_xbf) {
                if (tid < 64) tokl[tid] = tokens[(size_t)(row0 + tid) * TT + p];
                __syncthreads();
                const float* ep = emb + (size_t)tokl[w * 16 + n16] * EE + q8;
                #pragma unroll
                for (int kt = 0; kt < 8; kt++) {
                    float4 f0 = *(const float4*)(ep + kt * 32);
                    float4 f1 = *(const float4*)(ep + kt * 32 + 4);
                    union { unsigned short s[8]; short8 v; } u;
                    u.s[0]=f2bf(f0.x); u.s[1]=f2bf(f0.y); u.s[2]=f2bf(f0.z); u.s[3]=f2bf(f0.w);
                    u.s[4]=f2bf(f1.x); u.s[5]=f2bf(f1.y); u.s[6]=f2bf(f1.z); u.s[7]=f2bf(f1.w);
                    #pragma unroll
                    for (int gate = 0; gate < 4; gate++) {
                        short8 bv = *(const short8*)(wlane + (size_t)(gate * KT + kt) * 512);
                        acc[gate] = __builtin_amdgcn_mfma_f32_16x16x32_bf16(u.v, bv, acc[gate], 0, 0, 0);
                    }
                }
            } else {
                const unsigned short* xp = xbf + ((size_t)p * BB + myrow) * EE + q8;
                #pragma unroll
                for (int kt = 0; kt < 8; kt++)
                    xv[kt] = *(const short8*)(xp + kt * 32);
            }
        }

        if (layer == 0) {
            // ---- single-wave poll (wave 0), barrier release ----
            if (p < TT) {
                if (tid < 64) {
                    const int thr = p - pollSlack;
                    for (;;) {
                        bool bad = ((int)cldu(pollp) < thr);
                        if (__ballot(bad) == 0ULL) break;
                        __builtin_amdgcn_s_sleep(1);
                    }
                }
                __syncthreads();

                const unsigned short* h0r = h0buf + (size_t)(p & 7) * HS;   // h0(p)
                unsigned short* hw = h0buf + (size_t)((p + 1) & 7) * HS;
                const unsigned short* ah = h0r + (size_t)myrow * UU + q8;
                short8 hb[16];
                #pragma unroll
                for (int i = 0; i < 16; i++) hb[i] = cld16w(ah + i * 32);   // kt 8..23
                if (use_xbf) {   // x-MFMAs hide the h load RT (kt 0..7 first: order unchanged)
                    #pragma unroll
                    for (int kt = 0; kt < 8; kt++) {
                        #pragma unroll
                        for (int gate = 0; gate < 4; gate++) {
                            short8 bv = *(const short8*)(wlane + (size_t)(gate * KT + kt) * 512);
                            acc[gate] = __builtin_amdgcn_mfma_f32_16x16x32_bf16(xv[kt], bv, acc[gate], 0, 0, 0);
                        }
                    }
                }
                asm volatile("s_waitcnt vmcnt(0)" ::: "memory");
                __builtin_amdgcn_sched_barrier(0);
                #pragma unroll
                for (int i = 0; i < 16; i++) {
                    #pragma unroll
                    for (int gate = 0; gate < 4; gate++) {
                        short8 bv = *(const short8*)(wlane + (size_t)(gate * KT + 8 + i) * 512);
                        acc[gate] = __builtin_amdgcn_mfma_f32_16x16x32_bf16(hb[i], bv, acc[gate], 0, 0, 0);
                    }
                }

                // gating; stage h to LDS (stride 24)
                #pragma unroll
                for (int r = 0; r < 4; r++) {
                    float zi = acc[0][r];
                    float zf = acc[1][r];
                    float zg = acc[2][r];
                    float zo = acc[3][r];
                    float cn = sigf(zf) * cst[r] + sigf(zi) * tanhf(zg);
                    cst[r] = cn;
                    hst[(w * 16 + q * 4 + r) * 24 + n16] = f2bf(sigf(zo) * tanhf(cn));
                }
                __syncthreads();
                if (tid < 128) {
                    int row = tid >> 1, half = tid & 1;
                    u64x2 sv = *(const u64x2*)(hst + row * 24 + half * 8);
                    unsigned long long* dp = (unsigned long long*)
                        (hw + (size_t)(row0 + row) * UU + u0 + half * 8);
                    cst16w(dp, sv);
                }
            }
        } else {
            if (active) {
                const unsigned short* h0r = h0buf + (size_t)(p & 7) * HS;        // h0(p)
                const unsigned short* h1r = h1buf + (size_t)((p + 1) & 1) * HS;  // h1(p-1)
                unsigned short* hw = h1buf + (size_t)(p & 1) * HS;
                const unsigned short* a0 = h0r + (size_t)myrow * UU + q8;
                const unsigned short* a1 = h1r + (size_t)myrow * UU + q8;

                // ---- phase A: L0 flags >= p (lanes<32); usually instant ----
                for (;;) {
                    bool bad = (lane < 32) && ((int)cldu(pollp) < p);
                    if (__ballot(bad) == 0ULL) break;
                    __builtin_amdgcn_s_sleep(1);
                }
                short8 ha[16];
                #pragma unroll
                for (int i = 0; i < 16; i++) ha[i] = cld16w(a0 + i * 32);   // kt 0..15

                // ---- phase B: L1 flags >= p (lanes>=32); the binding wait ----
                for (;;) {
                    bool bad = (lane >= 32) && ((int)cldu(pollp) < p);
                    if (__ballot(bad) == 0ULL) break;
                    __builtin_amdgcn_s_sleep(1);
                }
                short8 hc[16];
                #pragma unroll
                for (int i = 0; i < 16; i++) hc[i] = cld16w(a1 + i * 32);   // kt 16..31

                asm volatile("s_waitcnt vmcnt(16)" ::: "memory");   // ha ready (hc in flight)
                __builtin_amdgcn_sched_barrier(0);
                #pragma unroll
                for (int i = 0; i < 16; i++) {
                    #pragma unroll
                    for (int gate = 0; gate < 4; gate++) {
                        short8 bv = *(const short8*)(wlane + (size_t)(gate * KT + i) * 512);
                        acc[gate] = __builtin_amdgcn_mfma_f32_16x16x32_bf16(ha[i], bv, acc[gate], 0, 0, 0);
                    }
                }
                asm volatile("s_waitcnt vmcnt(0)" ::: "memory");    // hc ready
                __builtin_amdgcn_sched_barrier(0);
                #pragma unroll
                for (int i = 0; i < 16; i++) {
                    #pragma unroll
                    for (int gate = 0; gate < 4; gate++) {
                        short8 bv = *(const short8*)(wlane + (size_t)(gate * KT + 16 + i) * 512);
                        acc[gate] = __builtin_amdgcn_mfma_f32_16x16x32_bf16(hc[i], bv, acc[gate], 0, 0, 0);
                    }
                }

                // gating; stage h to LDS (stride 24)
                #pragma unroll
                for (int r = 0; r < 4; r++) {
                    float zi = acc[0][r];
                    float zf = acc[1][r];
                    float zg = acc[2][r];
                    float zo = acc[3][r];
                    float cn = sigf(zf) * cst[r] + sigf(zi) * tanhf(zg);
                    cst[r] = cn;
                    hst[(w * 16 + q * 4 + r) * 24 + n16] = f2bf(sigf(zo) * tanhf(cn));
                }
                __syncthreads();
                if (tid < 128) {
                    int row = tid >> 1, half = tid & 1;
                    u64x2 sv = *(const u64x2*)(hst + row * 24 + half * 8);
                    unsigned long long* dp = (unsigned long long*)
                        (hw + (size_t)(row0 + row) * UU + u0 + half * 8);
                    cst16w(dp, sv);
                }
            }
        }

        // ---- arrive(p): every wave drains its own vmem, then tid0 flags ----
        if (p < TT) {
            asm volatile("s_waitcnt vmcnt(0)" ::: "memory");
            __syncthreads();
            if (tid == 0) cstu(myFlag, (unsigned int)(p + 1));
        }
    }
}

// ---------- final dense: out[b] = sigmoid(h1 . Wd + bd) ----------
__global__ __launch_bounds__(64) void dense_out(
    const unsigned short* __restrict__ h, const float* __restrict__ Wd,
    const float* __restrict__ bd, float* __restrict__ out)
{
    int b = blockIdx.x;
    int lane = threadIdx.x;
    float s = 0.f;
    #pragma unroll
    for (int k = lane; k < UU; k += 64) s += bf2f(h[(size_t)b * UU + k]) * Wd[k];
    #pragma unroll
    for (int off = 32; off > 0; off >>= 1) s += __shfl_down(s, off);
    if (lane == 0) out[b] = sigf(s + bd[0]);
}

extern "C" void kernel_launch(void* const* d_in, const int* in_sizes, int n_in,
                              void* d_out, int out_size, void* d_ws, size_t ws_size,
                              hipStream_t stream) {
    const int*   tokens = (const int*)  d_in[0];
    const float* emb    = (const float*)d_in[1];
    const float* W0     = (const float*)d_in[2];
    const float* U0     = (const float*)d_in[3];
    const float* b0     = (const float*)d_in[4];
    const float* W1     = (const float*)d_in[5];
    const float* U1     = (const float*)d_in[6];
    const float* b1     = (const float*)d_in[7];
    const float* Wd     = (const float*)d_in[8];
    const float* bd     = (const float*)d_in[9];
    float* out = (float*)d_out;

    // ws layout (bytes):
    // [Wt0 3MB][Wt1 4MB][h0 ring x8 2MB][h1 ring x2 0.5MB][bars 32KB][xbf 32MB]
    const size_t oWt0 = 0;
    const size_t oWt1 = (size_t)G4 * 768 * 2;                 // 3,145,728
    const size_t oH0  = oWt1 + (size_t)G4 * 1024 * 2;         // 7,340,032
    const size_t oH1  = oH0 + (size_t)8 * BB * UU * 2;        // +2,097,152
    const size_t oBar = oH1 + (size_t)2 * BB * UU * 2;        // +524,288
    const size_t oX   = oBar + 32768;
    const size_t needFull = oX + (size_t)TT * BB * EE * 2;    // ~43.5 MB
    int use_xbf = (ws_size >= needFull) ? 1 : 0;

    unsigned short* Wt0p = (unsigned short*)((char*)d_ws + oWt0);
    unsigned short* Wt1p = (unsigned short*)((char*)d_ws + oWt1);
    unsigned short* h0p  = (unsigned short*)((char*)d_ws + oH0);
    unsigned short* h1p  = (unsigned short*)((char*)d_ws + oH1);
    unsigned int*   barp = (unsigned int*)  ((char*)d_ws + oBar);
    unsigned short* xbfp = (unsigned short*)((char*)d_ws + oX);

    hipMemsetAsync((char*)d_ws + oH0, 0, oX - oH0, stream);

    wtrans<<<dim3(G4 / 32, EE / 32), dim3(32, 8), 0, stream>>>(W0, EE, Wt0p, 768, 0);
    wtrans<<<dim3(G4 / 32, UU / 32), dim3(32, 8), 0, stream>>>(U0, UU, Wt0p, 768, 256);
    wtrans<<<dim3(G4 / 32, UU / 32), dim3(32, 8), 0, stream>>>(W1, UU, Wt1p, 1024, 0);
    wtrans<<<dim3(G4 / 32, UU / 32), dim3(32, 8), 0, stream>>>(U1, UU, Wt1p, 1024, 512);

    if (use_xbf)
        xgather<<<dim3(BB * TT), dim3(64), 0, stream>>>(tokens, emb, xbfp);

    {
        const size_t shmem = 131072 + 3072 + 256;   // wl + hst + tokl
        hipFuncSetAttribute((const void*)rnn_persist,
                            hipFuncAttributeMaxDynamicSharedMemorySize, (int)shmem);
        void* args[] = {(void*)&Wt0p, (void*)&Wt1p, (void*)&xbfp,
                        (void*)&tokens, (void*)&emb, (void*)&b0, (void*)&b1,
                        (void*)&h0p, (void*)&h1p, (void*)&barp, (void*)&use_xbf};
        hipLaunchCooperativeKernel((const void*)rnn_persist, dim3(256), dim3(256),
                                   args, shmem, stream);
    }

    dense_out<<<dim3(BB), dim3(64), 0, stream>>>(h1p, Wd, bd, out);   // h1(256) = slot 0
}